// Round 1
// baseline (33.322 us; speedup 1.0000x reference)
//
#include <hip/hip_runtime.h>
#include <hip/hip_bf16.h>

// LongformerAttention (long-sequence path) reduces to:
//   out0 = hidden_states            (identity copy, B*S*H = 8,388,608 fp32)
//   out1 = zeros([B, S, S])         (33,554,432 fp32)
// d_out = concat(out0, out1) flat. global_attention_mask (d_in[1]) is unused.
//
// Pure memory movement: use the DMA/memset paths (graph-capture-legal async
// stream ops per the harness contract) instead of hand kernels.

extern "C" void kernel_launch(void* const* d_in, const int* in_sizes, int n_in,
                              void* d_out, int out_size, void* d_ws, size_t ws_size,
                              hipStream_t stream) {
    const float* hidden = (const float*)d_in[0];
    float* out = (float*)d_out;

    const size_t copy_elems = (size_t)in_sizes[0];              // B*S*H = 8,388,608
    const size_t zero_elems = (size_t)out_size - copy_elems;    // B*S*S = 33,554,432

    // out0: identity copy of hidden_states
    hipMemcpyAsync(out, hidden, copy_elems * sizeof(float),
                   hipMemcpyDeviceToDevice, stream);

    // out1: zeros — must be re-written every call (d_out poisoned once, graph replayed)
    hipMemsetAsync(out + copy_elems, 0, zero_elems * sizeof(float), stream);
}